// Round 5
// baseline (213.527 us; speedup 1.0000x reference)
//
#include <hip/hip_runtime.h>

#define IMG_H 512
#define IMG_W 512
#define NPLANES 24          // N*C = 8*3
#define ROWS_PER_BLK 16     // output rows per block
#define NITER 26            // ROWS_PER_BLK + 10 halo rows
#define NBLOCKS (32 * 24)
#define TOTAL_PIX 6291456.0f // 8*3*512*512

typedef float f32x2 __attribute__((ext_vector_type(2)));
typedef float f32x4 __attribute__((ext_vector_type(4)));

// Gaussian window, sigma=1.5, K=11, normalized (matches jnp reference to
// ~1e-7). constexpr so fully-unrolled taps fold weights to inline literals.
constexpr float GWc[11] = {
    0.00102838f, 0.00759876f, 0.03600050f, 0.10935817f, 0.21300535f,
    0.26601172f, 0.21300535f, 0.10935817f, 0.03600050f, 0.00759876f,
    0.00102838f};

// Design (round 5): the measured wall is HBM cold-miss latency (~900 cy)
// against ~180 cy of per-slot compute and a 1-slot-deep prefetch.
//  - depth-3 register prefetch (compile-time i%3 via full 26-slot unroll)
//    gives ~3 slots of vmcnt slack > HBM latency
//  - 2 output columns per thread: 256 threads cover the full 512-col row,
//    dwordx2 global loads, ds_write_b128 staging, 7x ds_read_b128 window
//  - LDS row is zero-padded at both edges (written once) so the inner loop
//    has no column masks and no halo loads at all
extern "C" __global__ __launch_bounds__(256) void ssim_structure_kernel(
    const float* __restrict__ x, const float* __restrict__ y,
    float* __restrict__ accum, unsigned int* __restrict__ counter,
    float* __restrict__ out) {
  const int tid = threadIdx.x;
  const int band = blockIdx.x;   // 0..31  (row band)
  const int plane = blockIdx.y;  // 0..23

  const size_t pbase = (size_t)plane * IMG_H * IMG_W;
  const float* __restrict__ xp = x + pbase;
  const float* __restrict__ yp = y + pbase;
  const int r0 = band * ROWS_PER_BLK;
  const int c0 = tid * 2;  // this thread's first output column

  // LDS row of interleaved (x,y) pairs, 2 pairs per f32x4.
  // f32x4 idx 0..3   = pair cols -8..-1  (zero pad)
  // f32x4 idx 4..259 = pair cols 0..511
  // f32x4 idx 260..263 = pair cols 512..519 (zero pad)
  __shared__ f32x4 lrow[2][264];

  // zero the edge pads of both buffers once (ordered before any read by the
  // first in-loop barrier)
  if (tid < 16) {
    const int b = tid >> 3, k = tid & 7;
    lrow[b][(k < 4) ? k : (256 + k)] = (f32x4){0.f, 0.f, 0.f, 0.f};
  }

  // circular register buffers of horizontal sums, per column
  f32x2 bm0[11], bq0[11], bm1[11], bq1[11];  // (Swx,Swy), (Swxx,Swyy)
  float bxy0[11], bxy1[11];                  // Swxy

  // depth-3 prefetch register sets (indices compile-time after full unroll)
  f32x2 ax[3], ay[3];

  float acc = 0.0f;

  auto loadrow = [&](int i, f32x2& vx, f32x2& vy) {
    const int hr = r0 - 5 + i;
    if ((i < NITER) && (hr >= 0) && (hr < IMG_H)) {  // wave-uniform
      const int off = hr * IMG_W + c0;
      vx = *reinterpret_cast<const f32x2*>(xp + off);
      vy = *reinterpret_cast<const f32x2*>(yp + off);
    } else {
      vx = (f32x2){0.f, 0.f};
      vy = (f32x2){0.f, 0.f};
    }
  };

  loadrow(0, ax[0], ay[0]);
  loadrow(1, ax[1], ay[1]);
  loadrow(2, ax[2], ay[2]);

#pragma unroll
  for (int i = 0; i < NITER; ++i) {
    const int s = i % 3;    // compile-time
    const int sel = i & 1;  // compile-time
    const int ii = i % 11;  // compile-time

    // stage row i (loaded 3 slots ago; vmcnt slack ~3 slots > HBM latency)
    f32x4 st;
    st.x = ax[s].x; st.y = ay[s].x;  // (x0,y0)
    st.z = ax[s].y; st.w = ay[s].y;  // (x1,y1)
    lrow[sel][4 + tid] = st;

    // issue row i+3 loads immediately
    loadrow(i + 3, ax[s], ay[s]);

    __syncthreads();

    // ---- horizontal pass: consume 7 x f32x4 = 14 pairs, window pair j
    // covers col c0-6+j; col0 tap d uses j=d+1, col1 tap d uses j=d+2 ----
    f32x2 tm0 = {0.f, 0.f}, tq0 = {0.f, 0.f};
    f32x2 tm1 = {0.f, 0.f}, tq1 = {0.f, 0.f};
    float txy0 = 0.f, txy1 = 0.f;

    auto tap = [&](const f32x2 v, int j) {  // j compile-time after unroll
      if (j >= 1 && j <= 11) {
        const float w = GWc[j - 1];
        const f32x2 wv = v * w;
        tm0 += wv;
        tq0 = __builtin_elementwise_fma(wv, v, tq0);
        txy0 = fmaf(wv.x, v.y, txy0);
      }
      if (j >= 2 && j <= 12) {
        const float w = GWc[j - 2];
        const f32x2 wv = v * w;
        tm1 += wv;
        tq1 = __builtin_elementwise_fma(wv, v, tq1);
        txy1 = fmaf(wv.x, v.y, txy1);
      }
    };

#pragma unroll
    for (int k = 0; k < 7; ++k) {
      const f32x4 q = lrow[sel][1 + tid + k];  // 16B/lane consecutive
      tap((f32x2){q.x, q.y}, 2 * k);
      tap((f32x2){q.z, q.w}, 2 * k + 1);
    }
    bm0[ii] = tm0; bq0[ii] = tq0; bxy0[ii] = txy0;
    bm1[ii] = tm1; bq1[ii] = tq1; bxy1[ii] = txy1;

    // ---- vertical pass + epilogue for output row r0 + (i - 10) ----
    if (i >= 10) {
      f32x2 vm0 = {0.f, 0.f}, vq0 = {0.f, 0.f};
      f32x2 vm1 = {0.f, 0.f}, vq1 = {0.f, 0.f};
      float vxy0 = 0.f, vxy1 = 0.f;
#pragma unroll
      for (int k = 0; k < 11; ++k) {
        const int s2 = (ii + 1 + k) % 11;  // compile-time
        const float w = GWc[k];
        const f32x2 w2 = {w, w};
        vm0 = __builtin_elementwise_fma(bm0[s2], w2, vm0);
        vq0 = __builtin_elementwise_fma(bq0[s2], w2, vq0);
        vxy0 = fmaf(w, bxy0[s2], vxy0);
        vm1 = __builtin_elementwise_fma(bm1[s2], w2, vm1);
        vq1 = __builtin_elementwise_fma(bq1[s2], w2, vq1);
        vxy1 = fmaf(w, bxy1[s2], vxy1);
      }
      // col 0
      {
        const float sxy = fmaf(-vm0.x, vm0.y, vxy0);
        f32x2 sp = __builtin_elementwise_fma(-vm0, vm0, vq0);
        sp = __builtin_elementwise_max(sp, (f32x2){1e-12f, 1e-12f});
        const float den = sqrtf(sp.x * sp.y) + 1e-4f;
        acc = fmaf(sxy + 1e-4f, __builtin_amdgcn_rcpf(den), acc);
      }
      // col 1
      {
        const float sxy = fmaf(-vm1.x, vm1.y, vxy1);
        f32x2 sp = __builtin_elementwise_fma(-vm1, vm1, vq1);
        sp = __builtin_elementwise_max(sp, (f32x2){1e-12f, 1e-12f});
        const float den = sqrtf(sp.x * sp.y) + 1e-4f;
        acc = fmaf(sxy + 1e-4f, __builtin_amdgcn_rcpf(den), acc);
      }
    }
  }

  // ---- block reduction: wave shuffle then cross-wave LDS ----
#pragma unroll
  for (int off = 32; off > 0; off >>= 1) acc += __shfl_down(acc, off, 64);
  __shared__ float wsum[4];
  if ((tid & 63) == 0) wsum[tid >> 6] = acc;
  __syncthreads();
  if (tid == 0) {
    float bsum = wsum[0] + wsum[1] + wsum[2] + wsum[3];
    atomicAdd(accum, bsum);
    __threadfence();
    const unsigned int ret = atomicAdd(counter, 1u);
    if (ret == (unsigned int)(NBLOCKS - 1)) {
      // all blocks' accum atomics are fenced-before their counter atomics,
      // so the running total is complete; atomic read bypasses stale caches
      __threadfence();
      const float total = atomicAdd(accum, 0.0f);
      out[0] = 1.0f - total * (1.0f / TOTAL_PIX);
    }
  }
}

extern "C" void kernel_launch(void* const* d_in, const int* in_sizes, int n_in,
                              void* d_out, int out_size, void* d_ws,
                              size_t ws_size, hipStream_t stream) {
  const float* x = (const float*)d_in[0];
  const float* y = (const float*)d_in[1];
  float* out = (float*)d_out;
  float* accum = (float*)d_ws;
  unsigned int* counter = (unsigned int*)((char*)d_ws + sizeof(float));

  hipMemsetAsync(d_ws, 0, 2 * sizeof(float), stream);

  dim3 grid(IMG_H / ROWS_PER_BLK, NPLANES);  // 32 x 24 = 768 blocks
  ssim_structure_kernel<<<grid, 256, 0, stream>>>(x, y, accum, counter, out);
}